// Round 1
// baseline (593.541 us; speedup 1.0000x reference)
//
#include <hip/hip_runtime.h>

#define N_DST 25000
#define E_NUM 400000

typedef __bf16 bf16x8 __attribute__((ext_vector_type(8)));
typedef __bf16 bf16x4 __attribute__((ext_vector_type(4)));
typedef float  f32x4  __attribute__((ext_vector_type(4)));

__device__ __forceinline__ float fast_cos(float x) {
  // cos(x), x in radians (|x| <= ~100): revolutions + fract + v_cos
  float r = x * 0.15915494309189535f;
  r = r - floorf(r);
  return __builtin_amdgcn_cosf(r);
}

// ---------------- prep kernels ----------------
__global__ __launch_bounds__(128) void cq_kernel(const float* __restrict__ Wq,
    const float* __restrict__ bq, const float* __restrict__ tb, float* __restrict__ cq) {
  int o = threadIdx.x;  // 128 threads
  float s = bq[o];
  for (int j = 0; j < 128; ++j) s += cosf(tb[j]) * Wq[o * 256 + 128 + j];
  cq[o] = s;
}

// Pack W rows into fragment-contiguous bf16 layout Bp[g][n][8], k = g*8+e.
__global__ __launch_bounds__(256) void pack_kernel(const float* __restrict__ W0,
    const float* __restrict__ W1, int srcStride, int N, int total, __bf16* __restrict__ Bp) {
  int idx = blockIdx.x * 256 + threadIdx.x;
  if (idx >= total) return;
  int g = idx / N, n = idx - g * N;
  const float* src = (W1 && n >= 128) ? (W1 + (size_t)(n - 128) * srcStride)
                                      : (W0 + (size_t)n * srcStride);
  const float4* s4 = reinterpret_cast<const float4*>(src + g * 8);
  float4 lo = s4[0], hi = s4[1];
  bf16x8 b;
  b[0] = (__bf16)lo.x; b[1] = (__bf16)lo.y; b[2] = (__bf16)lo.z; b[3] = (__bf16)lo.w;
  b[4] = (__bf16)hi.x; b[5] = (__bf16)hi.y; b[6] = (__bf16)hi.z; b[7] = (__bf16)hi.w;
  reinterpret_cast<bf16x8*>(Bp)[idx] = b;
}

// ---------------- CSR build ----------------
__global__ __launch_bounds__(256) void count_kernel(const int* __restrict__ dsti, int* __restrict__ counts) {
  int e = blockIdx.x * 256 + threadIdx.x;
  if (e < E_NUM) atomicAdd(&counts[dsti[e]], 1);
}

__global__ __launch_bounds__(256) void scan_kernel(const int* __restrict__ counts,
    int* __restrict__ offs, int* __restrict__ cursor) {
  __shared__ int buf[256];
  int tid = threadIdx.x;
  int carry = 0;
  for (int base = 0; base < N_DST; base += 256) {
    int x = (base + tid < N_DST) ? counts[base + tid] : 0;
    buf[tid] = x;
    __syncthreads();
    for (int o = 1; o < 256; o <<= 1) {
      int y = (tid >= o) ? buf[tid - o] : 0;
      __syncthreads();
      buf[tid] += y;
      __syncthreads();
    }
    int incl = buf[tid];
    int tot = buf[255];
    if (base + tid < N_DST) {
      int v = carry + incl - x;
      offs[base + tid] = v;
      cursor[base + tid] = v;
    }
    carry += tot;
    __syncthreads();
  }
  if (tid == 0) offs[N_DST] = carry;
}

__global__ __launch_bounds__(256) void fill_kernel(const int* __restrict__ dsti,
    int* __restrict__ cursor, int* __restrict__ elist) {
  int e = blockIdx.x * 256 + threadIdx.x;
  if (e < E_NUM) {
    int p = atomicAdd(&cursor[dsti[e]], 1);
    elist[p] = e;
  }
}

// ---------------- A-tile staging helper ----------------
template<int KP>
__device__ __forceinline__ void stage_seg(__bf16* Atile, int colOff,
    const float* __restrict__ src, int nv, int tid) {
  // 64 rows x 128 cols (float4 chunks), rows >= nv zero-filled
  for (int c = tid; c < 2048; c += 256) {
    int r = c >> 5;
    int c4 = (c & 31) << 2;
    float4 v;
    if (r < nv) v = *reinterpret_cast<const float4*>(src + (size_t)r * 128 + c4);
    else        v = make_float4(0.f, 0.f, 0.f, 0.f);
    bf16x4 b;
    b[0] = (__bf16)v.x; b[1] = (__bf16)v.y; b[2] = (__bf16)v.z; b[3] = (__bf16)v.w;
    *reinterpret_cast<bf16x4*>(&Atile[r * KP + colOff + c4]) = b;
  }
}

// ---------------- MFMA GEMM (3 modes) ----------------
// MODE 0: Qn = tgt @ Wq1^T + cq                  (K=128, N=128)
// MODE 1: [K|V] = kv_in @ [Wk|Wv]^T + b; score; V out  (K=384, N=256)
// MODE 2: rst = relu([h|tgt] @ Wout^T + bout)    (K=256, N=128)
template<int MODE>
__global__ __launch_bounds__(256) void gemm_kernel(
    const float* __restrict__ A0, const float* __restrict__ A1,
    const float* __restrict__ dtp, const float* __restrict__ tw, const float* __restrict__ tb,
    const __bf16* __restrict__ Bp,
    const float* __restrict__ bias0, const float* __restrict__ bias1,
    const int* __restrict__ dsti, const float* __restrict__ Qn,
    float* __restrict__ outF, __bf16* __restrict__ Vout, float* __restrict__ score)
{
  constexpr int KD = (MODE == 0) ? 128 : ((MODE == 1) ? 384 : 256);
  constexpr int NC = (MODE == 1) ? 256 : 128;
  constexpr int KP = KD + 8;           // padded LDS row (bf16 elems)
  constexpr int NFRAG = NC / 64;
  __shared__ __align__(16) __bf16 Atile[64 * KP];

  const int tid = threadIdx.x;
  const int row0 = blockIdx.x * 64;
  int nv;
  if constexpr (MODE == 1) nv = 64;
  else nv = min(64, N_DST - row0);

  if constexpr (MODE == 0) {
    stage_seg<KP>(Atile, 0, A0 + (size_t)row0 * 128, nv, tid);
  } else if constexpr (MODE == 2) {
    stage_seg<KP>(Atile, 0,   A0 + (size_t)row0 * 128, nv, tid);   // h
    stage_seg<KP>(Atile, 128, A1 + (size_t)row0 * 128, nv, tid);   // tgt
  } else {
    stage_seg<KP>(Atile, 0,   A0 + (size_t)(N_DST + row0) * 128, 64, tid);  // src rows
    stage_seg<KP>(Atile, 128, A1 + (size_t)row0 * 128, 64, tid);            // edge_f
    for (int c = tid; c < 64 * 128; c += 256) {                             // time feats
      int r = c >> 7, j = c & 127;
      float x = dtp[row0 + r] * tw[j] + tb[j];
      Atile[r * KP + 256 + j] = (__bf16)fast_cos(x);
    }
  }
  __syncthreads();

  const int lane = tid & 63;
  const int w = tid >> 6;
  const int nbase = w * (NC / 4);
  const int lrow = lane & 15;
  const int lk = lane >> 4;

  f32x4 acc[4][NFRAG];
#pragma unroll
  for (int mf = 0; mf < 4; ++mf)
#pragma unroll
    for (int nf = 0; nf < NFRAG; ++nf)
      acc[mf][nf] = (f32x4){0.f, 0.f, 0.f, 0.f};

#pragma unroll
  for (int kk = 0; kk < KD; kk += 32) {
    bf16x8 a[4];
#pragma unroll
    for (int mf = 0; mf < 4; ++mf)
      a[mf] = *reinterpret_cast<const bf16x8*>(&Atile[(mf * 16 + lrow) * KP + kk + lk * 8]);
#pragma unroll
    for (int nf = 0; nf < NFRAG; ++nf) {
      bf16x8 b = reinterpret_cast<const bf16x8*>(Bp)[((kk >> 3) + lk) * NC + nbase + nf * 16 + lrow];
#pragma unroll
      for (int mf = 0; mf < 4; ++mf)
        acc[mf][nf] = __builtin_amdgcn_mfma_f32_16x16x32_bf16(a[mf], b, acc[mf][nf], 0, 0, 0);
    }
  }

  if constexpr (MODE != 1) {
#pragma unroll
    for (int nf = 0; nf < NFRAG; ++nf) {
      int col = nbase + nf * 16 + lrow;
      float bb = bias0[col];
#pragma unroll
      for (int mf = 0; mf < 4; ++mf) {
#pragma unroll
        for (int r = 0; r < 4; ++r) {
          int row = mf * 16 + lk * 4 + r;
          if (row < nv) {
            float val = acc[mf][nf][r] + bb;
            if constexpr (MODE == 2) val = fmaxf(val, 0.f);
            outF[(size_t)(row0 + row) * 128 + col] = val;
          }
        }
      }
    }
  } else {
    __syncthreads();               // done reading Atile; reuse as K/V staging
    __bf16* Klds = Atile;          // [64][136]
    __bf16* Vlds = Atile + 64 * 136;
#pragma unroll
    for (int nf = 0; nf < NFRAG; ++nf) {
      int col = nbase + nf * 16 + lrow;
      float bb = (col < 128) ? bias0[col] : bias1[col - 128];
#pragma unroll
      for (int mf = 0; mf < 4; ++mf) {
#pragma unroll
        for (int r = 0; r < 4; ++r) {
          int row = mf * 16 + lk * 4 + r;
          float val = acc[mf][nf][r] + bb;
          if (col < 128) Klds[row * 136 + col] = (__bf16)val;
          else           Vlds[row * 136 + (col - 128)] = (__bf16)val;
        }
      }
    }
    __syncthreads();
    // V tile -> global (bf16, coalesced 16B chunks)
    for (int c = tid; c < 1024; c += 256) {
      int r = c >> 4, c8 = (c & 15) << 3;
      bf16x8 v = *reinterpret_cast<const bf16x8*>(&Vlds[r * 136 + c8]);
      *reinterpret_cast<bf16x8*>(&Vout[((size_t)(row0 + r) << 7) + c8]) = v;
    }
    // scores: thread (r, head) dots Q[dst] with K_lds row over 64 dims
    if (tid < 128) {
      int r = tid & 63, hh = tid >> 6;
      int d0 = hh << 6;
      int dst = dsti[row0 + r];
      const float4* q4 = reinterpret_cast<const float4*>(Qn + ((size_t)dst << 7) + d0);
      float s = 0.f;
#pragma unroll
      for (int c = 0; c < 8; ++c) {
        bf16x8 kv = *reinterpret_cast<const bf16x8*>(&Klds[r * 136 + d0 + c * 8]);
        float4 q0 = q4[2 * c], q1 = q4[2 * c + 1];
        s += q0.x * (float)kv[0] + q0.y * (float)kv[1] + q0.z * (float)kv[2] + q0.w * (float)kv[3];
        s += q1.x * (float)kv[4] + q1.y * (float)kv[5] + q1.z * (float)kv[6] + q1.w * (float)kv[7];
      }
      s = (s >= 0.f) ? s : 0.2f * s;   // leaky relu
      score[((size_t)(row0 + r) << 1) + hh] = s;
    }
  }
}

// ---------------- per-dst softmax + weighted V (CSR, 1 wave/dst) ----------------
__global__ __launch_bounds__(64) void agg_kernel(const int* __restrict__ offs,
    const int* __restrict__ elist, const float* __restrict__ score,
    const __bf16* __restrict__ V, float* __restrict__ h) {
  int d = blockIdx.x;
  int lane = threadIdx.x;
  int beg = offs[d], end = offs[d + 1];
  int n = end - beg;
  float m0 = -3.0e38f, m1 = -3.0e38f;
  for (int i = lane; i < n; i += 64) {
    int e = elist[beg + i];
    float2 sc = *reinterpret_cast<const float2*>(score + 2 * (size_t)e);
    m0 = fmaxf(m0, sc.x); m1 = fmaxf(m1, sc.y);
  }
#pragma unroll
  for (int o = 32; o; o >>= 1) {
    m0 = fmaxf(m0, __shfl_xor(m0, o));
    m1 = fmaxf(m1, __shfl_xor(m1, o));
  }
  float s0 = 0.f, s1 = 0.f;
  for (int i = lane; i < n; i += 64) {
    int e = elist[beg + i];
    float2 sc = *reinterpret_cast<const float2*>(score + 2 * (size_t)e);
    s0 += __expf(sc.x - m0); s1 += __expf(sc.y - m1);
  }
#pragma unroll
  for (int o = 32; o; o >>= 1) {
    s0 += __shfl_xor(s0, o);
    s1 += __shfl_xor(s1, o);
  }
  float inv0 = (n > 0) ? 1.f / s0 : 0.f;
  float inv1 = (n > 0) ? 1.f / s1 : 0.f;
  float a0 = 0.f, a1 = 0.f;
  for (int i = 0; i < n; ++i) {
    int e = elist[beg + i];
    float2 sc = *reinterpret_cast<const float2*>(score + 2 * (size_t)e);
    float w0 = __expf(sc.x - m0) * inv0;
    float w1 = __expf(sc.y - m1) * inv1;
    a0 += w0 * (float)V[(size_t)e * 128 + lane];        // head0 cols 0..63
    a1 += w1 * (float)V[(size_t)e * 128 + 64 + lane];   // head1 cols 64..127
  }
  h[(size_t)d * 128 + lane] = a0;
  h[(size_t)d * 128 + 64 + lane] = a1;
}

// ---------------- layernorm (relu already applied in MODE2) ----------------
__global__ __launch_bounds__(256) void ln_kernel(const float* __restrict__ rst,
    const float* __restrict__ gamma, const float* __restrict__ beta, float* __restrict__ out) {
  int row = blockIdx.x * 4 + (threadIdx.x >> 6);
  int lane = threadIdx.x & 63;
  float2 v = *reinterpret_cast<const float2*>(rst + (size_t)row * 128 + lane * 2);
  float sum = v.x + v.y;
  float sq = v.x * v.x + v.y * v.y;
#pragma unroll
  for (int o = 32; o; o >>= 1) {
    sum += __shfl_xor(sum, o);
    sq  += __shfl_xor(sq, o);
  }
  float mean = sum * (1.f / 128.f);
  float var = sq * (1.f / 128.f) - mean * mean;
  float rs = rsqrtf(var + 1e-5f);
  float2 g = *reinterpret_cast<const float2*>(gamma + lane * 2);
  float2 b = *reinterpret_cast<const float2*>(beta + lane * 2);
  float2 o2;
  o2.x = (v.x - mean) * rs * g.x + b.x;
  o2.y = (v.y - mean) * rs * g.y + b.y;
  *reinterpret_cast<float2*>(out + (size_t)row * 128 + lane * 2) = o2;
}

extern "C" void kernel_launch(void* const* d_in, const int* in_sizes, int n_in,
                              void* d_out, int out_size, void* d_ws, size_t ws_size,
                              hipStream_t stream) {
  (void)in_sizes; (void)n_in; (void)out_size; (void)ws_size;
  const float* node_h = (const float*)d_in[0];
  const float* edge_f = (const float*)d_in[1];
  const float* dtp    = (const float*)d_in[2];
  const int*   dsti   = (const int*)d_in[3];
  const float* tw     = (const float*)d_in[4];
  const float* tb     = (const float*)d_in[5];
  const float* Wq     = (const float*)d_in[6];
  const float* bq     = (const float*)d_in[7];
  const float* Wk     = (const float*)d_in[8];
  const float* bk     = (const float*)d_in[9];
  const float* Wv     = (const float*)d_in[10];
  const float* bv     = (const float*)d_in[11];
  const float* Wout   = (const float*)d_in[12];
  const float* bout   = (const float*)d_in[13];
  const float* gamma  = (const float*)d_in[14];
  const float* beta   = (const float*)d_in[15];
  float* outp = (float*)d_out;

  size_t off = 0;
  auto take = [&](size_t nbytes) -> void* {
    void* r = (char*)d_ws + off;
    off += (nbytes + 255) & ~(size_t)255;
    return r;
  };
  __bf16* Bp_kv  = (__bf16*)take((size_t)48 * 256 * 8 * 2);
  __bf16* Bp_q   = (__bf16*)take((size_t)16 * 128 * 8 * 2);
  __bf16* Bp_out = (__bf16*)take((size_t)32 * 128 * 8 * 2);
  float*  cq     = (float*)take(128 * 4);
  float*  Qn     = (float*)take((size_t)N_DST * 128 * 4);
  __bf16* Vbuf   = (__bf16*)take((size_t)E_NUM * 128 * 2);
  float*  score  = (float*)take((size_t)E_NUM * 2 * 4);
  int*    counts = (int*)take((size_t)N_DST * 4);
  int*    offs   = (int*)take((size_t)(N_DST + 1) * 4);
  int*    cursor = (int*)take((size_t)N_DST * 4);
  int*    elist  = (int*)take((size_t)E_NUM * 4);
  float*  hbuf   = (float*)take((size_t)N_DST * 128 * 4);
  float*  rst    = (float*)take((size_t)N_DST * 128 * 4);

  hipMemsetAsync(counts, 0, (size_t)N_DST * 4, stream);

  cq_kernel<<<1, 128, 0, stream>>>(Wq, bq, tb, cq);
  pack_kernel<<<(48 * 256 + 255) / 256, 256, 0, stream>>>(Wk, Wv, 384, 256, 48 * 256, Bp_kv);
  pack_kernel<<<(16 * 128 + 255) / 256, 256, 0, stream>>>(Wq, nullptr, 256, 128, 16 * 128, Bp_q);
  pack_kernel<<<(32 * 128 + 255) / 256, 256, 0, stream>>>(Wout, nullptr, 256, 128, 32 * 128, Bp_out);

  gemm_kernel<0><<<(N_DST + 63) / 64, 256, 0, stream>>>(node_h, nullptr, nullptr, nullptr, nullptr,
      Bp_q, cq, nullptr, nullptr, nullptr, Qn, nullptr, nullptr);
  gemm_kernel<1><<<E_NUM / 64, 256, 0, stream>>>(node_h, edge_f, dtp, tw, tb,
      Bp_kv, bk, bv, dsti, Qn, nullptr, Vbuf, score);

  count_kernel<<<(E_NUM + 255) / 256, 256, 0, stream>>>(dsti, counts);
  scan_kernel<<<1, 256, 0, stream>>>(counts, offs, cursor);
  fill_kernel<<<(E_NUM + 255) / 256, 256, 0, stream>>>(dsti, cursor, elist);
  agg_kernel<<<N_DST, 64, 0, stream>>>(offs, elist, score, Vbuf, hbuf);

  gemm_kernel<2><<<(N_DST + 63) / 64, 256, 0, stream>>>(hbuf, node_h, nullptr, nullptr, nullptr,
      Bp_out, bout, nullptr, nullptr, nullptr, rst, nullptr, nullptr);
  ln_kernel<<<N_DST / 4, 256, 0, stream>>>(rst, gamma, beta, outp);
}

// Round 2
// 403.895 us; speedup vs baseline: 1.4695x; 1.4695x over previous
//
#include <hip/hip_runtime.h>

#define N_DST 25000
#define E_NUM 400000

typedef __bf16 bf16x8 __attribute__((ext_vector_type(8)));
typedef __bf16 bf16x4 __attribute__((ext_vector_type(4)));
typedef __bf16 bf16x2 __attribute__((ext_vector_type(2)));
typedef float  f32x4  __attribute__((ext_vector_type(4)));

__device__ __forceinline__ float fast_cos(float x) {
  float r = x * 0.15915494309189535f;
  r = r - floorf(r);
  return __builtin_amdgcn_cosf(r);
}

// ---------------- prep kernels ----------------
__global__ __launch_bounds__(128) void cq_kernel(const float* __restrict__ Wq,
    const float* __restrict__ bq, const float* __restrict__ tb, float* __restrict__ cq) {
  int o = threadIdx.x;  // 128 threads
  float s = bq[o];
  for (int j = 0; j < 128; ++j) s += cosf(tb[j]) * Wq[o * 256 + 128 + j];
  cq[o] = s;
}

// Pack W rows into fragment-contiguous bf16 layout Bp[g][n][8], k = g*8+e.
__global__ __launch_bounds__(256) void pack_kernel(const float* __restrict__ W0,
    const float* __restrict__ W1, int srcStride, int N, int total, __bf16* __restrict__ Bp) {
  int idx = blockIdx.x * 256 + threadIdx.x;
  if (idx >= total) return;
  int g = idx / N, n = idx - g * N;
  const float* src = (W1 && n >= 128) ? (W1 + (size_t)(n - 128) * srcStride)
                                      : (W0 + (size_t)n * srcStride);
  const float4* s4 = reinterpret_cast<const float4*>(src + g * 8);
  float4 lo = s4[0], hi = s4[1];
  bf16x8 b;
  b[0] = (__bf16)lo.x; b[1] = (__bf16)lo.y; b[2] = (__bf16)lo.z; b[3] = (__bf16)lo.w;
  b[4] = (__bf16)hi.x; b[5] = (__bf16)hi.y; b[6] = (__bf16)hi.z; b[7] = (__bf16)hi.w;
  reinterpret_cast<bf16x8*>(Bp)[idx] = b;
}

// ---------------- CSR build ----------------
__global__ __launch_bounds__(256) void count_kernel(const int* __restrict__ dsti, int* __restrict__ counts) {
  int e = blockIdx.x * 256 + threadIdx.x;
  if (e < E_NUM) atomicAdd(&counts[dsti[e]], 1);
}

__global__ __launch_bounds__(1024) void scan_kernel(const int* __restrict__ counts,
    int* __restrict__ offs, int* __restrict__ cursor) {
  __shared__ int wpart[16];
  int tid = threadIdx.x, lane = tid & 63, wid = tid >> 6;
  int carry = 0;
  for (int base = 0; base < N_DST; base += 1024) {
    int idx = base + tid;
    int x = (idx < N_DST) ? counts[idx] : 0;
    int incl = x;
#pragma unroll
    for (int o = 1; o < 64; o <<= 1) {
      int y = __shfl_up(incl, o);
      if (lane >= o) incl += y;
    }
    if (lane == 63) wpart[wid] = incl;
    __syncthreads();
    if (wid == 0) {
      int v = (lane < 16) ? wpart[lane] : 0;
      int s = v;
#pragma unroll
      for (int o = 1; o < 16; o <<= 1) {
        int y = __shfl_up(s, o);
        if (lane >= o) s += y;
      }
      if (lane < 16) wpart[lane] = s;
    }
    __syncthreads();
    int woff = (wid > 0) ? wpart[wid - 1] : 0;
    int tot = wpart[15];
    if (idx < N_DST) {
      int v = carry + woff + incl - x;
      offs[idx] = v;
      cursor[idx] = v;
    }
    carry += tot;
    __syncthreads();
  }
  if (tid == 0) offs[N_DST] = carry;
}

__global__ __launch_bounds__(256) void fill_kernel(const int* __restrict__ dsti,
    int* __restrict__ cursor, int* __restrict__ elist, int* __restrict__ dsts) {
  int e = blockIdx.x * 256 + threadIdx.x;
  if (e < E_NUM) {
    int d = dsti[e];
    int p = atomicAdd(&cursor[d], 1);
    elist[p] = e;
    dsts[p] = d;
  }
}

// ---------------- MFMA GEMM (3 modes), LDS XOR-swizzled ----------------
// MODE 0: Qn = tgt @ Wq1^T + cq                         (K=128, N=128)
// MODE 1: sorted edges: [K|V] = kv_in @ [Wk|Wv]^T + b; score from acc; V out
// MODE 2: rst = relu([h|tgt] @ Wout^T + bout)           (K=256, N=128)
template<int MODE>
__global__ __launch_bounds__(256) void gemm_kernel(
    const float* __restrict__ A0, const float* __restrict__ A1,
    const float* __restrict__ dtp, const float* __restrict__ tw, const float* __restrict__ tb,
    const __bf16* __restrict__ Bp,
    const float* __restrict__ bias0, const float* __restrict__ bias1,
    const int* __restrict__ elist, const int* __restrict__ dsts,
    const float* __restrict__ Qn,
    float* __restrict__ outF, __bf16* __restrict__ Vout, float* __restrict__ score)
{
  constexpr int KD = (MODE == 0) ? 128 : ((MODE == 1) ? 384 : 256);
  constexpr int NC = (MODE == 1) ? 256 : 128;
  constexpr int KB = KD * 2;               // LDS row stride bytes
  constexpr int NFRAG = NC / 64;
  __shared__ __align__(16) char Atile[64 * KB];
  __shared__ int Elds[64];
  __shared__ int Dlds[64];
  __shared__ float dts[64];
  __shared__ float twl[128];
  __shared__ float tbl[128];

  const int tid = threadIdx.x;
  const int e0 = blockIdx.x * 64;
  const int nv = (MODE == 1) ? 64 : min(64, N_DST - e0);

  if constexpr (MODE == 1) {
    if (tid < 64) {
      int e = elist[e0 + tid];
      Elds[tid] = e;
      Dlds[tid] = dsts[e0 + tid];
      dts[tid] = dtp[e];
    } else if (tid < 192) {
      int j = tid - 64;
      twl[j] = tw[j];
      tbl[j] = tb[j];
    }
    __syncthreads();
    // issue the 16 row-gather loads first; cos (pure VALU+LDS) overlaps them
    float4 sv[8], ev[8];
#pragma unroll
    for (int i = 0; i < 8; ++i) {
      int c = tid + i * 256;
      int r = c >> 5, c4 = (c & 31) << 2;
      int eidx = Elds[r];
      sv[i] = *reinterpret_cast<const float4*>(A0 + ((size_t)N_DST + eidx) * 128 + c4);
      ev[i] = *reinterpret_cast<const float4*>(A1 + (size_t)eidx * 128 + c4);
    }
#pragma unroll
    for (int i = 0; i < 16; ++i) {
      int c2 = tid + i * 256;
      int r = c2 >> 6, j = (c2 & 63) << 1;
      float d = dts[r];
      bf16x2 p;
      p[0] = (__bf16)fast_cos(d * twl[j] + tbl[j]);
      p[1] = (__bf16)fast_cos(d * twl[j + 1] + tbl[j + 1]);
      *reinterpret_cast<bf16x2*>(Atile + r * KB + ((512 + j * 2) ^ ((r & 7) << 4))) = p;
    }
#pragma unroll
    for (int i = 0; i < 8; ++i) {
      int c = tid + i * 256;
      int r = c >> 5, c4 = (c & 31) << 2;
      bf16x4 b0, b1;
      b0[0] = (__bf16)sv[i].x; b0[1] = (__bf16)sv[i].y; b0[2] = (__bf16)sv[i].z; b0[3] = (__bf16)sv[i].w;
      b1[0] = (__bf16)ev[i].x; b1[1] = (__bf16)ev[i].y; b1[2] = (__bf16)ev[i].z; b1[3] = (__bf16)ev[i].w;
      *reinterpret_cast<bf16x4*>(Atile + r * KB + ((c4 * 2) ^ ((r & 7) << 4))) = b0;
      *reinterpret_cast<bf16x4*>(Atile + r * KB + ((256 + c4 * 2) ^ ((r & 7) << 4))) = b1;
    }
    __syncthreads();
  } else {
#pragma unroll
    for (int i = 0; i < 8; ++i) {
      int c = tid + i * 256;
      int r = c >> 5, c4 = (c & 31) << 2;
      float4 v0 = make_float4(0.f, 0.f, 0.f, 0.f);
      float4 v1 = make_float4(0.f, 0.f, 0.f, 0.f);
      if (r < nv) {
        v0 = *reinterpret_cast<const float4*>(A0 + (size_t)(e0 + r) * 128 + c4);
        if constexpr (MODE == 2)
          v1 = *reinterpret_cast<const float4*>(A1 + (size_t)(e0 + r) * 128 + c4);
      }
      bf16x4 b0;
      b0[0] = (__bf16)v0.x; b0[1] = (__bf16)v0.y; b0[2] = (__bf16)v0.z; b0[3] = (__bf16)v0.w;
      *reinterpret_cast<bf16x4*>(Atile + r * KB + ((c4 * 2) ^ ((r & 7) << 4))) = b0;
      if constexpr (MODE == 2) {
        bf16x4 b1;
        b1[0] = (__bf16)v1.x; b1[1] = (__bf16)v1.y; b1[2] = (__bf16)v1.z; b1[3] = (__bf16)v1.w;
        *reinterpret_cast<bf16x4*>(Atile + r * KB + ((256 + c4 * 2) ^ ((r & 7) << 4))) = b1;
      }
    }
    __syncthreads();
  }

  const int lane = tid & 63;
  const int w = tid >> 6;
  const int nbase = w * (NC / 4);
  const int lrow = lane & 15;
  const int lk = lane >> 4;
  const int aswz = (lrow & 7) << 4;   // row&7 == lrow&7 since mf*16 ≡ 0 (mod 8)

  f32x4 acc[4][NFRAG];
#pragma unroll
  for (int mf = 0; mf < 4; ++mf)
#pragma unroll
    for (int nf = 0; nf < NFRAG; ++nf)
      acc[mf][nf] = (f32x4){0.f, 0.f, 0.f, 0.f};

#pragma unroll
  for (int kk = 0; kk < KD; kk += 32) {
    bf16x8 b[NFRAG];
#pragma unroll
    for (int nf = 0; nf < NFRAG; ++nf)
      b[nf] = reinterpret_cast<const bf16x8*>(Bp)[((kk >> 3) + lk) * NC + nbase + nf * 16 + lrow];
    bf16x8 a[4];
#pragma unroll
    for (int mf = 0; mf < 4; ++mf)
      a[mf] = *reinterpret_cast<const bf16x8*>(
          Atile + (mf * 16 + lrow) * KB + (((kk + lk * 8) * 2) ^ aswz));
#pragma unroll
    for (int nf = 0; nf < NFRAG; ++nf)
#pragma unroll
      for (int mf = 0; mf < 4; ++mf)
        acc[mf][nf] = __builtin_amdgcn_mfma_f32_16x16x32_bf16(a[mf], b[nf], acc[mf][nf], 0, 0, 0);
  }

  if constexpr (MODE != 1) {
#pragma unroll
    for (int nf = 0; nf < NFRAG; ++nf) {
      int col = nbase + nf * 16 + lrow;
      float bb = bias0[col];
#pragma unroll
      for (int mf = 0; mf < 4; ++mf) {
#pragma unroll
        for (int r = 0; r < 4; ++r) {
          int row = mf * 16 + lk * 4 + r;
          if (row < nv) {
            float val = acc[mf][nf][r] + bb;
            if constexpr (MODE == 2) val = fmaxf(val, 0.f);
            outF[(size_t)(e0 + row) * 128 + col] = val;
          }
        }
      }
    }
  } else {
    __syncthreads();   // everyone done reading Atile
    if (w >= 2) {
      // waves 2,3 own V cols (w-2)*64 .. +63: bias + bf16 -> swizzled LDS bounce [64][128]
#pragma unroll
      for (int nf = 0; nf < 4; ++nf) {
        int vcol = (nbase - 128) + nf * 16 + lrow;
        float bb = bias1[vcol];
#pragma unroll
        for (int mf = 0; mf < 4; ++mf) {
#pragma unroll
          for (int r = 0; r < 4; ++r) {
            int row = mf * 16 + lk * 4 + r;
            *reinterpret_cast<__bf16*>(Atile + row * 256 + ((vcol * 2) ^ ((row & 7) << 4))) =
                (__bf16)(acc[mf][nf][r] + bb);
          }
        }
      }
    } else {
      // waves 0,1 own K head w: score = leaky(sum_d (K+bk)*Q[dst]) from registers
      float bkv[4];
#pragma unroll
      for (int nf = 0; nf < 4; ++nf) bkv[nf] = bias0[w * 64 + nf * 16 + lrow];
#pragma unroll
      for (int mf = 0; mf < 4; ++mf) {
#pragma unroll
        for (int r = 0; r < 4; ++r) {
          int row = mf * 16 + lk * 4 + r;
          const float* qrow = Qn + ((size_t)Dlds[row] << 7) + w * 64;
          float s = 0.f;
#pragma unroll
          for (int nf = 0; nf < 4; ++nf)
            s += (acc[mf][nf][r] + bkv[nf]) * qrow[nf * 16 + lrow];
          s += __shfl_xor(s, 1);
          s += __shfl_xor(s, 2);
          s += __shfl_xor(s, 4);
          s += __shfl_xor(s, 8);
          if (lrow == 0) {
            s = (s >= 0.f) ? s : 0.2f * s;
            score[((size_t)(e0 + row) << 1) + w] = s;
          }
        }
      }
    }
    __syncthreads();
    // V tile -> global (sorted edge space), coalesced 16B
#pragma unroll
    for (int i = 0; i < 4; ++i) {
      int c = tid + i * 256;
      int r = c >> 4, cb = (c & 15) << 4;
      bf16x8 v = *reinterpret_cast<const bf16x8*>(Atile + r * 256 + (cb ^ ((r & 7) << 4)));
      *reinterpret_cast<bf16x8*>(Vout + (((size_t)(e0 + r)) << 7) + (c & 15) * 8) = v;
    }
  }
}

// ---------------- per-dst softmax + weighted V (sorted, streaming) ----------------
__global__ __launch_bounds__(64) void agg_kernel(const int* __restrict__ offs,
    const float* __restrict__ score, const __bf16* __restrict__ V, float* __restrict__ h) {
  int d = blockIdx.x;
  int lane = threadIdx.x;
  int beg = offs[d], end = offs[d + 1];
  int n = end - beg;
  float m0 = -3.0e38f, m1 = -3.0e38f;
  for (int i = lane; i < n; i += 64) {
    float2 sc = *reinterpret_cast<const float2*>(score + 2 * (size_t)(beg + i));
    m0 = fmaxf(m0, sc.x); m1 = fmaxf(m1, sc.y);
  }
#pragma unroll
  for (int o = 32; o; o >>= 1) {
    m0 = fmaxf(m0, __shfl_xor(m0, o));
    m1 = fmaxf(m1, __shfl_xor(m1, o));
  }
  float s0 = 0.f, s1 = 0.f;
  for (int i = lane; i < n; i += 64) {
    float2 sc = *reinterpret_cast<const float2*>(score + 2 * (size_t)(beg + i));
    s0 += __expf(sc.x - m0); s1 += __expf(sc.y - m1);
  }
#pragma unroll
  for (int o = 32; o; o >>= 1) {
    s0 += __shfl_xor(s0, o);
    s1 += __shfl_xor(s1, o);
  }
  float inv0 = (n > 0) ? 1.f / s0 : 0.f;
  float inv1 = (n > 0) ? 1.f / s1 : 0.f;
  // 4 edges per iteration: quarter-wave q handles edge beg+i0+q, 16 lanes x 8 cols
  int q = lane >> 4, j = lane & 15;
  int hsel = j >> 3;   // 0: cols 0..63 (head0), 1: cols 64..127 (head1)
  float acc[8];
#pragma unroll
  for (int k2 = 0; k2 < 8; ++k2) acc[k2] = 0.f;
  for (int i0 = 0; i0 < n; i0 += 4) {
    int i = i0 + q;
    if (i < n) {
      size_t p = beg + i;
      float2 sc = *reinterpret_cast<const float2*>(score + 2 * p);
      float wgt = hsel ? __expf(sc.y - m1) * inv1 : __expf(sc.x - m0) * inv0;
      bf16x8 v = *reinterpret_cast<const bf16x8*>(V + (p << 7) + j * 8);
#pragma unroll
      for (int k2 = 0; k2 < 8; ++k2) acc[k2] += wgt * (float)v[k2];
    }
  }
#pragma unroll
  for (int k2 = 0; k2 < 8; ++k2) {
    acc[k2] += __shfl_xor(acc[k2], 16);
    acc[k2] += __shfl_xor(acc[k2], 32);
  }
  if (q == 0) {
    float4 lo = make_float4(acc[0], acc[1], acc[2], acc[3]);
    float4 hi = make_float4(acc[4], acc[5], acc[6], acc[7]);
    float* dst = h + ((size_t)d << 7) + j * 8;
    *reinterpret_cast<float4*>(dst) = lo;
    *reinterpret_cast<float4*>(dst + 4) = hi;
  }
}

// ---------------- layernorm (relu already applied in MODE2) ----------------
__global__ __launch_bounds__(256) void ln_kernel(const float* __restrict__ rst,
    const float* __restrict__ gamma, const float* __restrict__ beta, float* __restrict__ out) {
  int row = blockIdx.x * 4 + (threadIdx.x >> 6);
  int lane = threadIdx.x & 63;
  float2 v = *reinterpret_cast<const float2*>(rst + (size_t)row * 128 + lane * 2);
  float sum = v.x + v.y;
  float sq = v.x * v.x + v.y * v.y;
#pragma unroll
  for (int o = 32; o; o >>= 1) {
    sum += __shfl_xor(sum, o);
    sq  += __shfl_xor(sq, o);
  }
  float mean = sum * (1.f / 128.f);
  float var = sq * (1.f / 128.f) - mean * mean;
  float rs = rsqrtf(var + 1e-5f);
  float2 g = *reinterpret_cast<const float2*>(gamma + lane * 2);
  float2 b = *reinterpret_cast<const float2*>(beta + lane * 2);
  float2 o2;
  o2.x = (v.x - mean) * rs * g.x + b.x;
  o2.y = (v.y - mean) * rs * g.y + b.y;
  *reinterpret_cast<float2*>(out + (size_t)row * 128 + lane * 2) = o2;
}

extern "C" void kernel_launch(void* const* d_in, const int* in_sizes, int n_in,
                              void* d_out, int out_size, void* d_ws, size_t ws_size,
                              hipStream_t stream) {
  (void)in_sizes; (void)n_in; (void)out_size; (void)ws_size;
  const float* node_h = (const float*)d_in[0];
  const float* edge_f = (const float*)d_in[1];
  const float* dtp    = (const float*)d_in[2];
  const int*   dsti   = (const int*)d_in[3];
  const float* tw     = (const float*)d_in[4];
  const float* tb     = (const float*)d_in[5];
  const float* Wq     = (const float*)d_in[6];
  const float* bq     = (const float*)d_in[7];
  const float* Wk     = (const float*)d_in[8];
  const float* bk     = (const float*)d_in[9];
  const float* Wv     = (const float*)d_in[10];
  const float* bv     = (const float*)d_in[11];
  const float* Wout   = (const float*)d_in[12];
  const float* bout   = (const float*)d_in[13];
  const float* gamma  = (const float*)d_in[14];
  const float* beta   = (const float*)d_in[15];
  float* outp = (float*)d_out;

  size_t off = 0;
  auto take = [&](size_t nbytes) -> void* {
    void* r = (char*)d_ws + off;
    off += (nbytes + 255) & ~(size_t)255;
    return r;
  };
  __bf16* Bp_kv  = (__bf16*)take((size_t)48 * 256 * 8 * 2);
  __bf16* Bp_q   = (__bf16*)take((size_t)16 * 128 * 8 * 2);
  __bf16* Bp_out = (__bf16*)take((size_t)32 * 128 * 8 * 2);
  float*  cq     = (float*)take(128 * 4);
  float*  Qn     = (float*)take((size_t)N_DST * 128 * 4);
  __bf16* Vbuf   = (__bf16*)take((size_t)E_NUM * 128 * 2);
  float*  score  = (float*)take((size_t)E_NUM * 2 * 4);
  int*    counts = (int*)take((size_t)N_DST * 4);
  int*    offs   = (int*)take((size_t)(N_DST + 1) * 4);
  int*    cursor = (int*)take((size_t)N_DST * 4);
  int*    elist  = (int*)take((size_t)E_NUM * 4);
  int*    dsts   = (int*)take((size_t)E_NUM * 4);
  float*  hbuf   = (float*)take((size_t)N_DST * 128 * 4);
  float*  rst    = (float*)take((size_t)N_DST * 128 * 4);

  hipMemsetAsync(counts, 0, (size_t)N_DST * 4, stream);

  cq_kernel<<<1, 128, 0, stream>>>(Wq, bq, tb, cq);
  pack_kernel<<<(48 * 256 + 255) / 256, 256, 0, stream>>>(Wk, Wv, 384, 256, 48 * 256, Bp_kv);
  pack_kernel<<<(16 * 128 + 255) / 256, 256, 0, stream>>>(Wq, nullptr, 256, 128, 16 * 128, Bp_q);
  pack_kernel<<<(32 * 128 + 255) / 256, 256, 0, stream>>>(Wout, nullptr, 256, 128, 32 * 128, Bp_out);

  count_kernel<<<(E_NUM + 255) / 256, 256, 0, stream>>>(dsti, counts);
  scan_kernel<<<1, 1024, 0, stream>>>(counts, offs, cursor);
  fill_kernel<<<(E_NUM + 255) / 256, 256, 0, stream>>>(dsti, cursor, elist, dsts);

  gemm_kernel<0><<<(N_DST + 63) / 64, 256, 0, stream>>>(node_h, nullptr, nullptr, nullptr, nullptr,
      Bp_q, cq, nullptr, nullptr, nullptr, nullptr, Qn, nullptr, nullptr);
  gemm_kernel<1><<<E_NUM / 64, 256, 0, stream>>>(node_h, edge_f, dtp, tw, tb,
      Bp_kv, bk, bv, elist, dsts, Qn, nullptr, Vbuf, score);

  agg_kernel<<<N_DST, 64, 0, stream>>>(offs, score, Vbuf, hbuf);

  gemm_kernel<2><<<(N_DST + 63) / 64, 256, 0, stream>>>(hbuf, node_h, nullptr, nullptr, nullptr,
      Bp_out, bout, nullptr, nullptr, nullptr, nullptr, rst, nullptr, nullptr);
  ln_kernel<<<N_DST / 4, 256, 0, stream>>>(rst, gamma, beta, outp);
}

// Round 3
// 368.876 us; speedup vs baseline: 1.6091x; 1.0949x over previous
//
#include <hip/hip_runtime.h>

#define N_DST 25000
#define E_NUM 400000

typedef __bf16 bf16x8 __attribute__((ext_vector_type(8)));
typedef __bf16 bf16x4 __attribute__((ext_vector_type(4)));
typedef __bf16 bf16x2 __attribute__((ext_vector_type(2)));
typedef float  f32x4  __attribute__((ext_vector_type(4)));

__device__ __forceinline__ float fast_cos(float x) {
  float r = x * 0.15915494309189535f;
  r = r - floorf(r);
  return __builtin_amdgcn_cosf(r);
}

// ---------------- prep kernels ----------------
__global__ __launch_bounds__(128) void cq_kernel(const float* __restrict__ Wq,
    const float* __restrict__ bq, const float* __restrict__ tb, float* __restrict__ cq) {
  int o = threadIdx.x;  // 128 threads
  float s = bq[o];
  for (int j = 0; j < 128; ++j) s += cosf(tb[j]) * Wq[o * 256 + 128 + j];
  cq[o] = s;
}

// Pack W rows into fragment-contiguous bf16 layout Bp[g][n][8], k = g*8+e.
__global__ __launch_bounds__(256) void pack_kernel(const float* __restrict__ W0,
    const float* __restrict__ W1, int srcStride, int N, int total, __bf16* __restrict__ Bp) {
  int idx = blockIdx.x * 256 + threadIdx.x;
  if (idx >= total) return;
  int g = idx / N, n = idx - g * N;
  const float* src = (W1 && n >= 128) ? (W1 + (size_t)(n - 128) * srcStride)
                                      : (W0 + (size_t)n * srcStride);
  const float4* s4 = reinterpret_cast<const float4*>(src + g * 8);
  float4 lo = s4[0], hi = s4[1];
  bf16x8 b;
  b[0] = (__bf16)lo.x; b[1] = (__bf16)lo.y; b[2] = (__bf16)lo.z; b[3] = (__bf16)lo.w;
  b[4] = (__bf16)hi.x; b[5] = (__bf16)hi.y; b[6] = (__bf16)hi.z; b[7] = (__bf16)hi.w;
  reinterpret_cast<bf16x8*>(Bp)[idx] = b;
}

// ---------------- CSR build ----------------
__global__ __launch_bounds__(256) void count_kernel(const int* __restrict__ dsti, int* __restrict__ counts) {
  int e = blockIdx.x * 256 + threadIdx.x;
  if (e < E_NUM) atomicAdd(&counts[dsti[e]], 1);
}

__global__ __launch_bounds__(1024) void scan_kernel(const int* __restrict__ counts,
    int* __restrict__ offs, int* __restrict__ cursor) {
  __shared__ int wpart[16];
  int tid = threadIdx.x, lane = tid & 63, wid = tid >> 6;
  int carry = 0;
  for (int base = 0; base < N_DST; base += 1024) {
    int idx = base + tid;
    int x = (idx < N_DST) ? counts[idx] : 0;
    int incl = x;
#pragma unroll
    for (int o = 1; o < 64; o <<= 1) {
      int y = __shfl_up(incl, o);
      if (lane >= o) incl += y;
    }
    if (lane == 63) wpart[wid] = incl;
    __syncthreads();
    if (wid == 0) {
      int v = (lane < 16) ? wpart[lane] : 0;
      int s = v;
#pragma unroll
      for (int o = 1; o < 16; o <<= 1) {
        int y = __shfl_up(s, o);
        if (lane >= o) s += y;
      }
      if (lane < 16) wpart[lane] = s;
    }
    __syncthreads();
    int woff = (wid > 0) ? wpart[wid - 1] : 0;
    int tot = wpart[15];
    if (idx < N_DST) {
      int v = carry + woff + incl - x;
      offs[idx] = v;
      cursor[idx] = v;
    }
    carry += tot;
    __syncthreads();
  }
  if (tid == 0) offs[N_DST] = carry;
}

__global__ __launch_bounds__(256) void fill_kernel(const int* __restrict__ dsti,
    int* __restrict__ cursor, int* __restrict__ elist, int* __restrict__ dsts) {
  int e = blockIdx.x * 256 + threadIdx.x;
  if (e < E_NUM) {
    int d = dsti[e];
    int p = atomicAdd(&cursor[d], 1);
    elist[p] = e;
    dsts[p] = d;
  }
}

// ---------------- MFMA GEMM (3 modes), LDS XOR-swizzled, SW-pipelined ----------------
// MODE 0: Qn = tgt @ Wq1^T + cq                         (K=128, N=128)
// MODE 1: sorted edges: [K|V] = kv_in @ [Wk|Wv]^T + b; score from acc; V out
// MODE 2: out = LN(relu([h|tgt] @ Wout^T + bout))       (K=256, N=128; dtp=gamma, tw=beta)
template<int MODE>
__global__ __launch_bounds__(256, 3) void gemm_kernel(
    const float* __restrict__ A0, const float* __restrict__ A1,
    const float* __restrict__ dtp, const float* __restrict__ tw, const float* __restrict__ tb,
    const __bf16* __restrict__ Bp,
    const float* __restrict__ bias0, const float* __restrict__ bias1,
    const int* __restrict__ elist, const int* __restrict__ dsts,
    const float* __restrict__ Qn,
    float* __restrict__ outF, __bf16* __restrict__ Vout, float* __restrict__ score)
{
  constexpr int KD = (MODE == 0) ? 128 : ((MODE == 1) ? 384 : 256);
  constexpr int NC = (MODE == 1) ? 256 : 128;
  constexpr int KB = KD * 2;               // LDS row stride bytes
  constexpr int NFRAG = NC / 64;
  constexpr int NK = KD / 32;
  __shared__ __align__(16) char Atile[64 * KB];
  __shared__ int Elds[64];
  __shared__ int Dlds[64];
  __shared__ float dts[64];
  __shared__ float twl[128];
  __shared__ float tbl[128];

  const int tid = threadIdx.x;
  const int e0 = blockIdx.x * 64;
  const int nv = (MODE == 1) ? 64 : min(64, N_DST - e0);

  if constexpr (MODE == 1) {
    if (tid < 64) {
      int e = elist[e0 + tid];
      Elds[tid] = e;
      Dlds[tid] = dsts[e0 + tid];
      dts[tid] = dtp[e];
    } else if (tid < 192) {
      int j = tid - 64;
      twl[j] = tw[j];
      tbl[j] = tb[j];
    }
    __syncthreads();
    // issue the 16 row-gather loads first; cos (pure VALU+LDS) overlaps them
    float4 sv[8], ev[8];
#pragma unroll
    for (int i = 0; i < 8; ++i) {
      int c = tid + i * 256;
      int r = c >> 5, c4 = (c & 31) << 2;
      int eidx = Elds[r];
      sv[i] = *reinterpret_cast<const float4*>(A0 + ((size_t)N_DST + eidx) * 128 + c4);
      ev[i] = *reinterpret_cast<const float4*>(A1 + (size_t)eidx * 128 + c4);
    }
    // cos: row-per-thread so dts is hoisted; float2 reads of tw/tb
    {
      int r = tid >> 2;
      int j0 = (tid & 3) << 5;
      float d = dts[r];
      char* rowb = Atile + r * KB;
      int swz = (r & 7) << 4;
      const float2* tw2 = reinterpret_cast<const float2*>(twl);
      const float2* tb2 = reinterpret_cast<const float2*>(tbl);
#pragma unroll
      for (int i = 0; i < 16; ++i) {
        int j = j0 + i * 2;
        float2 wv = tw2[j >> 1], bv = tb2[j >> 1];
        bf16x2 p;
        p[0] = (__bf16)fast_cos(d * wv.x + bv.x);
        p[1] = (__bf16)fast_cos(d * wv.y + bv.y);
        *reinterpret_cast<bf16x2*>(rowb + ((512 + j * 2) ^ swz)) = p;
      }
    }
#pragma unroll
    for (int i = 0; i < 8; ++i) {
      int c = tid + i * 256;
      int r = c >> 5, c4 = (c & 31) << 2;
      bf16x4 b0, b1;
      b0[0] = (__bf16)sv[i].x; b0[1] = (__bf16)sv[i].y; b0[2] = (__bf16)sv[i].z; b0[3] = (__bf16)sv[i].w;
      b1[0] = (__bf16)ev[i].x; b1[1] = (__bf16)ev[i].y; b1[2] = (__bf16)ev[i].z; b1[3] = (__bf16)ev[i].w;
      *reinterpret_cast<bf16x4*>(Atile + r * KB + ((c4 * 2) ^ ((r & 7) << 4))) = b0;
      *reinterpret_cast<bf16x4*>(Atile + r * KB + ((256 + c4 * 2) ^ ((r & 7) << 4))) = b1;
    }
    __syncthreads();
  } else {
#pragma unroll
    for (int i = 0; i < 8; ++i) {
      int c = tid + i * 256;
      int r = c >> 5, c4 = (c & 31) << 2;
      float4 v0 = make_float4(0.f, 0.f, 0.f, 0.f);
      float4 v1 = make_float4(0.f, 0.f, 0.f, 0.f);
      if (r < nv) {
        v0 = *reinterpret_cast<const float4*>(A0 + (size_t)(e0 + r) * 128 + c4);
        if constexpr (MODE == 2)
          v1 = *reinterpret_cast<const float4*>(A1 + (size_t)(e0 + r) * 128 + c4);
      }
      bf16x4 b0;
      b0[0] = (__bf16)v0.x; b0[1] = (__bf16)v0.y; b0[2] = (__bf16)v0.z; b0[3] = (__bf16)v0.w;
      *reinterpret_cast<bf16x4*>(Atile + r * KB + ((c4 * 2) ^ ((r & 7) << 4))) = b0;
      if constexpr (MODE == 2) {
        bf16x4 b1;
        b1[0] = (__bf16)v1.x; b1[1] = (__bf16)v1.y; b1[2] = (__bf16)v1.z; b1[3] = (__bf16)v1.w;
        *reinterpret_cast<bf16x4*>(Atile + r * KB + ((256 + c4 * 2) ^ ((r & 7) << 4))) = b1;
      }
    }
    __syncthreads();
  }

  const int lane = tid & 63;
  const int w = tid >> 6;
  const int nbase = w * (NC / 4);
  const int lrow = lane & 15;
  const int lk = lane >> 4;
  const int aswz = (lrow & 7) << 4;   // row&7 == lrow&7 since mf*16 ≡ 0 (mod 8)

  f32x4 acc[4][NFRAG];
#pragma unroll
  for (int mf = 0; mf < 4; ++mf)
#pragma unroll
    for (int nf = 0; nf < NFRAG; ++nf)
      acc[mf][nf] = (f32x4){0.f, 0.f, 0.f, 0.f};

  // ---- software-pipelined K-loop: B 2 steps ahead (L2), A 1 step ahead (LDS) ----
  const bf16x8* Bb = reinterpret_cast<const bf16x8*>(Bp) + (size_t)lk * NC + nbase + lrow;
  bf16x8 bq[3][NFRAG];
  bf16x8 aq[2][4];
  auto loadB = [&](int ks) {
#pragma unroll
    for (int nf = 0; nf < NFRAG; ++nf)
      bq[ks % 3][nf] = Bb[(size_t)ks * 4 * NC + nf * 16];
  };
  auto loadA = [&](int ks) {
#pragma unroll
    for (int mf = 0; mf < 4; ++mf)
      aq[ks % 2][mf] = *reinterpret_cast<const bf16x8*>(
          Atile + (mf * 16 + lrow) * KB + (((ks * 32 + lk * 8) * 2) ^ aswz));
  };
  loadB(0);
  if (NK > 1) loadB(1);
  loadA(0);
#pragma unroll
  for (int ks = 0; ks < NK; ++ks) {
    if (ks + 2 < NK) loadB(ks + 2);
    if (ks + 1 < NK) loadA(ks + 1);
#pragma unroll
    for (int nf = 0; nf < NFRAG; ++nf)
#pragma unroll
      for (int mf = 0; mf < 4; ++mf)
        acc[mf][nf] = __builtin_amdgcn_mfma_f32_16x16x32_bf16(aq[ks % 2][mf], bq[ks % 3][nf],
                                                              acc[mf][nf], 0, 0, 0);
  }

  if constexpr (MODE == 0) {
#pragma unroll
    for (int nf = 0; nf < NFRAG; ++nf) {
      int col = nbase + nf * 16 + lrow;
      float bb = bias0[col];
#pragma unroll
      for (int mf = 0; mf < 4; ++mf) {
#pragma unroll
        for (int r = 0; r < 4; ++r) {
          int row = mf * 16 + lk * 4 + r;
          if (row < nv)
            outF[(size_t)(e0 + row) * 128 + col] = acc[mf][nf][r] + bb;
        }
      }
    }
  } else if constexpr (MODE == 2) {
    // fused relu + layernorm epilogue
    const float* gammaP = dtp;
    const float* betaP = tw;
    float vals[2][4][4];   // [nf][mf][r]
#pragma unroll
    for (int nf = 0; nf < 2; ++nf) {
      float bb = bias0[nbase + nf * 16 + lrow];
#pragma unroll
      for (int mf = 0; mf < 4; ++mf)
#pragma unroll
        for (int r = 0; r < 4; ++r)
          vals[nf][mf][r] = fmaxf(acc[mf][nf][r] + bb, 0.f);
    }
    __syncthreads();   // done reading Atile; reuse for reductions
    float* sums = reinterpret_cast<float*>(Atile);          // [4][64]
    float* sqs  = reinterpret_cast<float*>(Atile) + 256;    // [4][64]
    float* stats = reinterpret_cast<float*>(Atile) + 512;   // [64][2]
#pragma unroll
    for (int mf = 0; mf < 4; ++mf) {
#pragma unroll
      for (int r = 0; r < 4; ++r) {
        float s1 = vals[0][mf][r] + vals[1][mf][r];
        float s2 = vals[0][mf][r] * vals[0][mf][r] + vals[1][mf][r] * vals[1][mf][r];
#pragma unroll
        for (int o = 1; o < 16; o <<= 1) {
          s1 += __shfl_xor(s1, o);
          s2 += __shfl_xor(s2, o);
        }
        if (lrow == 0) {
          int row = mf * 16 + lk * 4 + r;
          sums[w * 64 + row] = s1;
          sqs[w * 64 + row] = s2;
        }
      }
    }
    __syncthreads();
    if (tid < 64) {
      float s = sums[tid] + sums[64 + tid] + sums[128 + tid] + sums[192 + tid];
      float q = sqs[tid] + sqs[64 + tid] + sqs[128 + tid] + sqs[192 + tid];
      float mean = s * (1.f / 128.f);
      float var = q * (1.f / 128.f) - mean * mean;
      stats[tid * 2] = mean;
      stats[tid * 2 + 1] = rsqrtf(var + 1e-5f);
    }
    __syncthreads();
#pragma unroll
    for (int nf = 0; nf < 2; ++nf) {
      int col = nbase + nf * 16 + lrow;
      float g = gammaP[col], b = betaP[col];
#pragma unroll
      for (int mf = 0; mf < 4; ++mf) {
#pragma unroll
        for (int r = 0; r < 4; ++r) {
          int row = mf * 16 + lk * 4 + r;
          if (row < nv) {
            float mean = stats[row * 2], rs = stats[row * 2 + 1];
            outF[(size_t)(e0 + row) * 128 + col] = (vals[nf][mf][r] - mean) * rs * g + b;
          }
        }
      }
    }
  } else {
    __syncthreads();   // everyone done reading Atile
    if (w >= 2) {
      // waves 2,3 own V cols (w-2)*64 .. +63: bias + bf16 -> swizzled LDS bounce [64][128]
#pragma unroll
      for (int nf = 0; nf < 4; ++nf) {
        int vcol = (nbase - 128) + nf * 16 + lrow;
        float bb = bias1[vcol];
#pragma unroll
        for (int mf = 0; mf < 4; ++mf) {
#pragma unroll
          for (int r = 0; r < 4; ++r) {
            int row = mf * 16 + lk * 4 + r;
            *reinterpret_cast<__bf16*>(Atile + row * 256 + ((vcol * 2) ^ ((row & 7) << 4))) =
                (__bf16)(acc[mf][nf][r] + bb);
          }
        }
      }
    } else {
      // waves 0,1 own K head w: score = leaky(sum_d (K+bk)*Q[dst]) from registers
      float bkv[4];
#pragma unroll
      for (int nf = 0; nf < 4; ++nf) bkv[nf] = bias0[w * 64 + nf * 16 + lrow];
#pragma unroll
      for (int mf = 0; mf < 4; ++mf) {
#pragma unroll
        for (int r = 0; r < 4; ++r) {
          int row = mf * 16 + lk * 4 + r;
          const float* qrow = Qn + ((size_t)Dlds[row] << 7) + w * 64;
          float s = 0.f;
#pragma unroll
          for (int nf = 0; nf < 4; ++nf)
            s += (acc[mf][nf][r] + bkv[nf]) * qrow[nf * 16 + lrow];
          s += __shfl_xor(s, 1);
          s += __shfl_xor(s, 2);
          s += __shfl_xor(s, 4);
          s += __shfl_xor(s, 8);
          if (lrow == 0) {
            s = (s >= 0.f) ? s : 0.2f * s;
            score[((size_t)(e0 + row) << 1) + w] = s;
          }
        }
      }
    }
    __syncthreads();
    // V tile -> global (sorted edge space), coalesced 16B
#pragma unroll
    for (int i = 0; i < 4; ++i) {
      int c = tid + i * 256;
      int r = c >> 4, cb = (c & 15) << 4;
      bf16x8 v = *reinterpret_cast<const bf16x8*>(Atile + r * 256 + (cb ^ ((r & 7) << 4)));
      *reinterpret_cast<bf16x8*>(Vout + (((size_t)(e0 + r)) << 7) + (c & 15) * 8) = v;
    }
  }
}

// ---------------- per-dst softmax + weighted V (sorted, streaming; 4 dst/block) ----------------
__global__ __launch_bounds__(256) void agg_kernel(const int* __restrict__ offs,
    const float* __restrict__ score, const __bf16* __restrict__ V, float* __restrict__ h) {
  int d = blockIdx.x * 4 + (threadIdx.x >> 6);
  if (d >= N_DST) return;
  int lane = threadIdx.x & 63;
  int beg = offs[d], end = offs[d + 1];
  int n = end - beg;
  float m0 = -3.0e38f, m1 = -3.0e38f;
  for (int i = lane; i < n; i += 64) {
    float2 sc = *reinterpret_cast<const float2*>(score + 2 * (size_t)(beg + i));
    m0 = fmaxf(m0, sc.x); m1 = fmaxf(m1, sc.y);
  }
#pragma unroll
  for (int o = 32; o; o >>= 1) {
    m0 = fmaxf(m0, __shfl_xor(m0, o));
    m1 = fmaxf(m1, __shfl_xor(m1, o));
  }
  float s0 = 0.f, s1 = 0.f;
  for (int i = lane; i < n; i += 64) {
    float2 sc = *reinterpret_cast<const float2*>(score + 2 * (size_t)(beg + i));
    s0 += __expf(sc.x - m0); s1 += __expf(sc.y - m1);
  }
#pragma unroll
  for (int o = 32; o; o >>= 1) {
    s0 += __shfl_xor(s0, o);
    s1 += __shfl_xor(s1, o);
  }
  float inv0 = (n > 0) ? 1.f / s0 : 0.f;
  float inv1 = (n > 0) ? 1.f / s1 : 0.f;
  // 4 edges per iteration: quarter-wave q handles edge beg+i0+q, 16 lanes x 8 cols
  int q = lane >> 4, j = lane & 15;
  int hsel = j >> 3;   // 0: cols 0..63 (head0), 1: cols 64..127 (head1)
  float acc[8];
#pragma unroll
  for (int k2 = 0; k2 < 8; ++k2) acc[k2] = 0.f;
  for (int i0 = 0; i0 < n; i0 += 4) {
    int i = i0 + q;
    if (i < n) {
      size_t p = beg + i;
      float2 sc = *reinterpret_cast<const float2*>(score + 2 * p);
      float wgt = hsel ? __expf(sc.y - m1) * inv1 : __expf(sc.x - m0) * inv0;
      bf16x8 v = *reinterpret_cast<const bf16x8*>(V + (p << 7) + j * 8);
#pragma unroll
      for (int k2 = 0; k2 < 8; ++k2) acc[k2] += wgt * (float)v[k2];
    }
  }
#pragma unroll
  for (int k2 = 0; k2 < 8; ++k2) {
    acc[k2] += __shfl_xor(acc[k2], 16);
    acc[k2] += __shfl_xor(acc[k2], 32);
  }
  if (q == 0) {
    float4 lo = make_float4(acc[0], acc[1], acc[2], acc[3]);
    float4 hi = make_float4(acc[4], acc[5], acc[6], acc[7]);
    float* dst = h + ((size_t)d << 7) + j * 8;
    *reinterpret_cast<float4*>(dst) = lo;
    *reinterpret_cast<float4*>(dst + 4) = hi;
  }
}

extern "C" void kernel_launch(void* const* d_in, const int* in_sizes, int n_in,
                              void* d_out, int out_size, void* d_ws, size_t ws_size,
                              hipStream_t stream) {
  (void)in_sizes; (void)n_in; (void)out_size; (void)ws_size;
  const float* node_h = (const float*)d_in[0];
  const float* edge_f = (const float*)d_in[1];
  const float* dtp    = (const float*)d_in[2];
  const int*   dsti   = (const int*)d_in[3];
  const float* tw     = (const float*)d_in[4];
  const float* tb     = (const float*)d_in[5];
  const float* Wq     = (const float*)d_in[6];
  const float* bq     = (const float*)d_in[7];
  const float* Wk     = (const float*)d_in[8];
  const float* bk     = (const float*)d_in[9];
  const float* Wv     = (const float*)d_in[10];
  const float* bv     = (const float*)d_in[11];
  const float* Wout   = (const float*)d_in[12];
  const float* bout   = (const float*)d_in[13];
  const float* gamma  = (const float*)d_in[14];
  const float* beta   = (const float*)d_in[15];
  float* outp = (float*)d_out;

  size_t off = 0;
  auto take = [&](size_t nbytes) -> void* {
    void* r = (char*)d_ws + off;
    off += (nbytes + 255) & ~(size_t)255;
    return r;
  };
  __bf16* Bp_kv  = (__bf16*)take((size_t)48 * 256 * 8 * 2);
  __bf16* Bp_q   = (__bf16*)take((size_t)16 * 128 * 8 * 2);
  __bf16* Bp_out = (__bf16*)take((size_t)32 * 128 * 8 * 2);
  float*  cq     = (float*)take(128 * 4);
  float*  Qn     = (float*)take((size_t)N_DST * 128 * 4);
  __bf16* Vbuf   = (__bf16*)take((size_t)E_NUM * 128 * 2);
  float*  score  = (float*)take((size_t)E_NUM * 2 * 4);
  int*    counts = (int*)take((size_t)N_DST * 4);
  int*    offs   = (int*)take((size_t)(N_DST + 1) * 4);
  int*    cursor = (int*)take((size_t)N_DST * 4);
  int*    elist  = (int*)take((size_t)E_NUM * 4);
  int*    dsts   = (int*)take((size_t)E_NUM * 4);
  float*  hbuf   = (float*)take((size_t)N_DST * 128 * 4);

  hipMemsetAsync(counts, 0, (size_t)N_DST * 4, stream);

  cq_kernel<<<1, 128, 0, stream>>>(Wq, bq, tb, cq);
  pack_kernel<<<(48 * 256 + 255) / 256, 256, 0, stream>>>(Wk, Wv, 384, 256, 48 * 256, Bp_kv);
  pack_kernel<<<(16 * 128 + 255) / 256, 256, 0, stream>>>(Wq, nullptr, 256, 128, 16 * 128, Bp_q);
  pack_kernel<<<(32 * 128 + 255) / 256, 256, 0, stream>>>(Wout, nullptr, 256, 128, 32 * 128, Bp_out);

  count_kernel<<<(E_NUM + 255) / 256, 256, 0, stream>>>(dsti, counts);
  scan_kernel<<<1, 1024, 0, stream>>>(counts, offs, cursor);
  fill_kernel<<<(E_NUM + 255) / 256, 256, 0, stream>>>(dsti, cursor, elist, dsts);

  gemm_kernel<0><<<(N_DST + 63) / 64, 256, 0, stream>>>(node_h, nullptr, nullptr, nullptr, nullptr,
      Bp_q, cq, nullptr, nullptr, nullptr, nullptr, Qn, nullptr, nullptr);
  gemm_kernel<1><<<E_NUM / 64, 256, 0, stream>>>(node_h, edge_f, dtp, tw, tb,
      Bp_kv, bk, bv, elist, dsts, Qn, nullptr, Vbuf, score);

  agg_kernel<<<(N_DST + 3) / 4, 256, 0, stream>>>(offs, score, Vbuf, hbuf);

  gemm_kernel<2><<<(N_DST + 63) / 64, 256, 0, stream>>>(hbuf, node_h, gamma, beta, nullptr,
      Bp_out, bout, nullptr, nullptr, nullptr, nullptr, outp, nullptr, nullptr);
}

// Round 4
// 340.995 us; speedup vs baseline: 1.7406x; 1.0818x over previous
//
#include <hip/hip_runtime.h>

#define N_DST 25000
#define E_NUM 400000

typedef __bf16 bf16x8 __attribute__((ext_vector_type(8)));
typedef __bf16 bf16x4 __attribute__((ext_vector_type(4)));
typedef __bf16 bf16x2 __attribute__((ext_vector_type(2)));
typedef float  f32x4  __attribute__((ext_vector_type(4)));

__device__ __forceinline__ float fast_cos(float x) {
  float r = x * 0.15915494309189535f;
  r = r - floorf(r);
  return __builtin_amdgcn_cosf(r);
}

// pack W into frag-contiguous bf16: out[fid*64+lane] = W[n][g*8..g*8+7]
// fid = (ks*4 + w)*NFRAGW + nf; n = w*(NC/4)+nf*16+(lane&15); g = ks*4+(lane>>4)
__device__ __forceinline__ void pack_frag(const float* __restrict__ W0,
    const float* __restrict__ W1, int stride, int NC, int idx, __bf16* __restrict__ out) {
  int lane = idx & 63, fid = idx >> 6;
  int nfw = NC >> 6;
  int perks = nfw << 2;
  int ks = fid / perks, rem = fid - ks * perks;
  int w = rem / nfw, nf = rem - w * nfw;
  int n = w * (NC >> 2) + nf * 16 + (lane & 15);
  int g = (ks << 2) + (lane >> 4);
  const float* src = (W1 && n >= 128) ? (W1 + (size_t)(n - 128) * stride)
                                      : (W0 + (size_t)n * stride);
  const float4* s4 = reinterpret_cast<const float4*>(src + g * 8);
  float4 lo = s4[0], hi = s4[1];
  bf16x8 b;
  b[0]=(__bf16)lo.x; b[1]=(__bf16)lo.y; b[2]=(__bf16)lo.z; b[3]=(__bf16)lo.w;
  b[4]=(__bf16)hi.x; b[5]=(__bf16)hi.y; b[6]=(__bf16)hi.z; b[7]=(__bf16)hi.w;
  reinterpret_cast<bf16x8*>(out)[idx] = b;
}

// one kernel: cq + 3 B-repacks + edge counting
__global__ __launch_bounds__(256) void prep_kernel(
    const float* __restrict__ Wq, const float* __restrict__ bq, const float* __restrict__ tb,
    const float* __restrict__ Wk, const float* __restrict__ Wv, const float* __restrict__ Wout,
    const int* __restrict__ dsti,
    float* __restrict__ cq, __bf16* __restrict__ Bq_kv, __bf16* __restrict__ Bq_q,
    __bf16* __restrict__ Bq_out, int* __restrict__ counts) {
  int b = blockIdx.x, tid = threadIdx.x;
  if (b == 0) {
    if (tid < 128) {
      float s = bq[tid];
      for (int j = 0; j < 128; ++j) s += cosf(tb[j]) * Wq[tid * 256 + 128 + j];
      cq[tid] = s;
    }
    return;
  }
  b -= 1;
  if (b < 48) { pack_frag(Wk, Wv, 384, 256, b * 256 + tid, Bq_kv); return; }
  b -= 48;
  if (b < 8)  { pack_frag(Wq, nullptr, 256, 128, b * 256 + tid, Bq_q); return; }
  b -= 8;
  if (b < 16) { pack_frag(Wout, nullptr, 256, 128, b * 256 + tid, Bq_out); return; }
  b -= 16;
  int e = b * 256 + tid;
  if (e < E_NUM) atomicAdd(&counts[dsti[e]], 1);
}

__global__ __launch_bounds__(1024) void scan_kernel(const int* __restrict__ counts,
    int* __restrict__ offs, int* __restrict__ cursor) {
  __shared__ int wpart[16];
  int tid = threadIdx.x, lane = tid & 63, wid = tid >> 6;
  int carry = 0;
  for (int base = 0; base < N_DST; base += 1024) {
    int idx = base + tid;
    int x = (idx < N_DST) ? counts[idx] : 0;
    int incl = x;
#pragma unroll
    for (int o = 1; o < 64; o <<= 1) {
      int y = __shfl_up(incl, o);
      if (lane >= o) incl += y;
    }
    if (lane == 63) wpart[wid] = incl;
    __syncthreads();
    if (wid == 0) {
      int v = (lane < 16) ? wpart[lane] : 0;
      int s = v;
#pragma unroll
      for (int o = 1; o < 16; o <<= 1) {
        int y = __shfl_up(s, o);
        if (lane >= o) s += y;
      }
      if (lane < 16) wpart[lane] = s;
    }
    __syncthreads();
    int woff = (wid > 0) ? wpart[wid - 1] : 0;
    int tot = wpart[15];
    if (idx < N_DST) {
      int v = carry + woff + incl - x;
      offs[idx] = v;
      cursor[idx] = v;
    }
    carry += tot;
    __syncthreads();
  }
  if (tid == 0) offs[N_DST] = carry;
}

__global__ __launch_bounds__(256) void fill_kernel(const int* __restrict__ dsti,
    int* __restrict__ cursor, int* __restrict__ elist, int* __restrict__ dsts) {
  int e = blockIdx.x * 256 + threadIdx.x;
  if (e < E_NUM) {
    int d = dsti[e];
    int p = atomicAdd(&cursor[d], 1);
    elist[p] = e;
    dsts[p] = d;
  }
}

// ---------------- MFMA GEMM, 128-wide K-tiles, double-buffered LDS ----------------
// MODE 0: Qn = tgt @ Wq1^T + cq                 (tiles: tgt)
// MODE 1: [K|V] = kv_in @ [Wk|Wv]^T; score; V   (tiles: src, edge, cos)
// MODE 2: out = LN(relu([h|tgt] @ Wout^T+bout)) (tiles: h, tgt; dtp=gamma, tw=beta)
template<int MODE>
__global__ __launch_bounds__(256, 4) void gemm_kernel(
    const float* __restrict__ A0, const float* __restrict__ A1,
    const float* __restrict__ dtp, const float* __restrict__ tw, const float* __restrict__ tb,
    const __bf16* __restrict__ Bq,
    const float* __restrict__ bias0, const float* __restrict__ bias1,
    const int* __restrict__ elist, const int* __restrict__ dsts,
    const float* __restrict__ Qn,
    float* __restrict__ outF, __bf16* __restrict__ Vout, float* __restrict__ score)
{
  constexpr int NC = (MODE == 1) ? 256 : 128;
  constexpr int NFRAGW = NC / 64;
  __shared__ __align__(16) char Abuf[2][64 * 256];
  __shared__ int Elds[64];
  __shared__ int Dlds[64];
  __shared__ float dts[64];
  __shared__ float twl[128];
  __shared__ float tbl[128];

  const int tid = threadIdx.x;
  const int e0 = blockIdx.x * 64;
  const int nv = (MODE == 1) ? 64 : min(64, N_DST - e0);
  const int srow = tid >> 5;
  const int sc4 = (tid & 31) << 2;

  const int lane = tid & 63;
  const int w = tid >> 6;
  const int nbase = w * (NC / 4);
  const int lrow = lane & 15;
  const int lk = lane >> 4;
  const int aswz = (lrow & 7) << 4;
  const bf16x8* __restrict__ Bw =
      reinterpret_cast<const bf16x8*>(Bq) + (size_t)(w * NFRAGW) * 64 + lane;

  f32x4 acc[4][NFRAGW];
#pragma unroll
  for (int mf = 0; mf < 4; ++mf)
#pragma unroll
    for (int nf = 0; nf < NFRAGW; ++nf)
      acc[mf][nf] = (f32x4){0.f, 0.f, 0.f, 0.f};

  auto issueA = [&](int t, float4 (&v)[8]) {
    if constexpr (MODE == 1) {
      const float* base = (t == 0) ? (A0 + (size_t)N_DST * 128) : A1;
#pragma unroll
      for (int i = 0; i < 8; ++i)
        v[i] = *reinterpret_cast<const float4*>(base + (size_t)Elds[srow + i * 8] * 128 + sc4);
    } else {
      const float* base = (t == 0) ? A0 : A1;
#pragma unroll
      for (int i = 0; i < 8; ++i) {
        int r = srow + i * 8;
        v[i] = (r < nv) ? *reinterpret_cast<const float4*>(base + (size_t)(e0 + r) * 128 + sc4)
                        : make_float4(0.f, 0.f, 0.f, 0.f);
      }
    }
  };
  auto writeA = [&](char* buf, float4 (&v)[8]) {
#pragma unroll
    for (int i = 0; i < 8; ++i) {
      int r = srow + i * 8;
      bf16x4 b;
      b[0]=(__bf16)v[i].x; b[1]=(__bf16)v[i].y; b[2]=(__bf16)v[i].z; b[3]=(__bf16)v[i].w;
      *reinterpret_cast<bf16x4*>(buf + r * 256 + ((sc4 * 2) ^ ((r & 7) << 4))) = b;
    }
  };
  auto cosW = [&](char* buf) {
    int r = tid >> 2;
    int j0 = (tid & 3) << 5;
    float d = dts[r];
    char* rowb = buf + r * 256;
    int swz = (r & 7) << 4;
#pragma unroll
    for (int i = 0; i < 16; ++i) {
      int j = j0 + i * 2;
      bf16x2 p;
      p[0] = (__bf16)fast_cos(d * twl[j] + tbl[j]);
      p[1] = (__bf16)fast_cos(d * twl[j + 1] + tbl[j + 1]);
      *reinterpret_cast<bf16x2*>(rowb + ((j * 2) ^ swz)) = p;
    }
  };
  auto ktile = [&](const char* buf, int t) {
#pragma unroll
    for (int ks = 0; ks < 4; ++ks) {
      bf16x8 b[NFRAGW];
#pragma unroll
      for (int nf = 0; nf < NFRAGW; ++nf)
        b[nf] = Bw[((size_t)(t * 4 + ks) * 4 * NFRAGW + nf) * 64];
      bf16x8 a[4];
#pragma unroll
      for (int mf = 0; mf < 4; ++mf)
        a[mf] = *reinterpret_cast<const bf16x8*>(
            buf + (mf * 16 + lrow) * 256 + (((ks * 32 + lk * 8) * 2) ^ aswz));
#pragma unroll
      for (int nf = 0; nf < NFRAGW; ++nf)
#pragma unroll
        for (int mf = 0; mf < 4; ++mf)
          acc[mf][nf] = __builtin_amdgcn_mfma_f32_16x16x32_bf16(a[mf], b[nf], acc[mf][nf], 0, 0, 0);
    }
  };

  if constexpr (MODE == 1) {
    if (tid < 64) {
      int e = elist[e0 + tid];
      Elds[tid] = e;
      Dlds[tid] = dsts[e0 + tid];
      dts[tid] = dtp[e];
    } else if (tid < 192) {
      int j = tid - 64;
      twl[j] = tw[j];
      tbl[j] = tb[j];
    }
    __syncthreads();
    float4 v[8];
    issueA(0, v);
    writeA(Abuf[0], v);
    __syncthreads();
    issueA(1, v);              // edge loads fly under src MFMAs
    ktile(Abuf[0], 0);
    writeA(Abuf[1], v);
    __syncthreads();
    ktile(Abuf[1], 1);
    cosW(Abuf[0]);             // time tile: pure VALU, overlaps other waves' MFMAs
    __syncthreads();
    ktile(Abuf[0], 2);
    // ---- epilogue: scores from registers (waves 0,1), V via LDS bounce (waves 2,3)
    __syncthreads();
    if (w >= 2) {
#pragma unroll
      for (int nf = 0; nf < NFRAGW; ++nf) {
        int vcol = (nbase - 128) + nf * 16 + lrow;
        float bb = bias1[vcol];
#pragma unroll
        for (int mf = 0; mf < 4; ++mf) {
#pragma unroll
          for (int r = 0; r < 4; ++r) {
            int row = mf * 16 + lk * 4 + r;
            *reinterpret_cast<__bf16*>(Abuf[0] + row * 256 + ((vcol * 2) ^ ((row & 7) << 4))) =
                (__bf16)(acc[mf][nf][r] + bb);
          }
        }
      }
    } else {
      float bkv[NFRAGW];
#pragma unroll
      for (int nf = 0; nf < NFRAGW; ++nf) bkv[nf] = bias0[nbase + nf * 16 + lrow];
#pragma unroll
      for (int mf = 0; mf < 4; ++mf) {
#pragma unroll
        for (int r = 0; r < 4; ++r) {
          int row = mf * 16 + lk * 4 + r;
          const float* qrow = Qn + ((size_t)Dlds[row] << 7) + w * 64;
          float s = 0.f;
#pragma unroll
          for (int nf = 0; nf < NFRAGW; ++nf)
            s += (acc[mf][nf][r] + bkv[nf]) * qrow[nf * 16 + lrow];
          s += __shfl_xor(s, 1);
          s += __shfl_xor(s, 2);
          s += __shfl_xor(s, 4);
          s += __shfl_xor(s, 8);
          if (lrow == 0) {
            s = (s >= 0.f) ? s : 0.2f * s;
            score[((size_t)(e0 + row) << 1) + w] = s;
          }
        }
      }
    }
    __syncthreads();
#pragma unroll
    for (int i = 0; i < 4; ++i) {
      int c = tid + i * 256;
      int r = c >> 4, cb = (c & 15) << 4;
      bf16x8 vv = *reinterpret_cast<const bf16x8*>(Abuf[0] + r * 256 + (cb ^ ((r & 7) << 4)));
      *reinterpret_cast<bf16x8*>(Vout + (((size_t)(e0 + r)) << 7) + (c & 15) * 8) = vv;
    }
  } else if constexpr (MODE == 0) {
    float4 v[8];
    issueA(0, v);
    writeA(Abuf[0], v);
    __syncthreads();
    ktile(Abuf[0], 0);
#pragma unroll
    for (int nf = 0; nf < NFRAGW; ++nf) {
      int col = nbase + nf * 16 + lrow;
      float bb = bias0[col];
#pragma unroll
      for (int mf = 0; mf < 4; ++mf) {
#pragma unroll
        for (int r = 0; r < 4; ++r) {
          int row = mf * 16 + lk * 4 + r;
          if (row < nv)
            outF[(size_t)(e0 + row) * 128 + col] = acc[mf][nf][r] + bb;
        }
      }
    }
  } else {
    float4 v[8];
    issueA(0, v);
    writeA(Abuf[0], v);
    __syncthreads();
    issueA(1, v);
    ktile(Abuf[0], 0);
    writeA(Abuf[1], v);
    __syncthreads();
    ktile(Abuf[1], 1);
    // ---- fused relu + layernorm epilogue
    const float* gammaP = dtp;
    const float* betaP = tw;
    float vals[NFRAGW][4][4];
#pragma unroll
    for (int nf = 0; nf < NFRAGW; ++nf) {
      float bb = bias0[nbase + nf * 16 + lrow];
#pragma unroll
      for (int mf = 0; mf < 4; ++mf)
#pragma unroll
        for (int r = 0; r < 4; ++r)
          vals[nf][mf][r] = fmaxf(acc[mf][nf][r] + bb, 0.f);
    }
    __syncthreads();
    float* sums = reinterpret_cast<float*>(Abuf[0]);
    float* sqs  = reinterpret_cast<float*>(Abuf[0]) + 256;
    float* stats = reinterpret_cast<float*>(Abuf[0]) + 512;
#pragma unroll
    for (int mf = 0; mf < 4; ++mf) {
#pragma unroll
      for (int r = 0; r < 4; ++r) {
        float s1 = vals[0][mf][r] + vals[1][mf][r];
        float s2 = vals[0][mf][r] * vals[0][mf][r] + vals[1][mf][r] * vals[1][mf][r];
#pragma unroll
        for (int o = 1; o < 16; o <<= 1) {
          s1 += __shfl_xor(s1, o);
          s2 += __shfl_xor(s2, o);
        }
        if (lrow == 0) {
          int row = mf * 16 + lk * 4 + r;
          sums[w * 64 + row] = s1;
          sqs[w * 64 + row] = s2;
        }
      }
    }
    __syncthreads();
    if (tid < 64) {
      float s = sums[tid] + sums[64 + tid] + sums[128 + tid] + sums[192 + tid];
      float q = sqs[tid] + sqs[64 + tid] + sqs[128 + tid] + sqs[192 + tid];
      float mean = s * (1.f / 128.f);
      float var = q * (1.f / 128.f) - mean * mean;
      stats[tid * 2] = mean;
      stats[tid * 2 + 1] = rsqrtf(var + 1e-5f);
    }
    __syncthreads();
#pragma unroll
    for (int nf = 0; nf < NFRAGW; ++nf) {
      int col = nbase + nf * 16 + lrow;
      float g = gammaP[col], bC = betaP[col];
#pragma unroll
      for (int mf = 0; mf < 4; ++mf) {
#pragma unroll
        for (int r = 0; r < 4; ++r) {
          int row = mf * 16 + lk * 4 + r;
          if (row < nv) {
            float mean = stats[row * 2], rs = stats[row * 2 + 1];
            outF[(size_t)(e0 + row) * 128 + col] = (vals[nf][mf][r] - mean) * rs * g + bC;
          }
        }
      }
    }
  }
}

// ---------------- per-dst softmax + weighted V (sorted, streaming; 4 dst/block) ----------------
__global__ __launch_bounds__(256) void agg_kernel(const int* __restrict__ offs,
    const float* __restrict__ score, const __bf16* __restrict__ V, float* __restrict__ h) {
  int d = blockIdx.x * 4 + (threadIdx.x >> 6);
  if (d >= N_DST) return;
  int lane = threadIdx.x & 63;
  int beg = offs[d], end = offs[d + 1];
  int n = end - beg;
  float m0 = -3.0e38f, m1 = -3.0e38f;
  for (int i = lane; i < n; i += 64) {
    float2 sc = *reinterpret_cast<const float2*>(score + 2 * (size_t)(beg + i));
    m0 = fmaxf(m0, sc.x); m1 = fmaxf(m1, sc.y);
  }
#pragma unroll
  for (int o = 32; o; o >>= 1) {
    m0 = fmaxf(m0, __shfl_xor(m0, o));
    m1 = fmaxf(m1, __shfl_xor(m1, o));
  }
  float s0 = 0.f, s1 = 0.f;
  for (int i = lane; i < n; i += 64) {
    float2 sc = *reinterpret_cast<const float2*>(score + 2 * (size_t)(beg + i));
    s0 += __expf(sc.x - m0); s1 += __expf(sc.y - m1);
  }
#pragma unroll
  for (int o = 32; o; o >>= 1) {
    s0 += __shfl_xor(s0, o);
    s1 += __shfl_xor(s1, o);
  }
  float inv0 = (n > 0) ? 1.f / s0 : 0.f;
  float inv1 = (n > 0) ? 1.f / s1 : 0.f;
  int q = lane >> 4, j = lane & 15;
  int hsel = j >> 3;
  float acc[8];
#pragma unroll
  for (int k2 = 0; k2 < 8; ++k2) acc[k2] = 0.f;
  for (int i0 = 0; i0 < n; i0 += 4) {
    int i = i0 + q;
    if (i < n) {
      size_t p = beg + i;
      float2 sc = *reinterpret_cast<const float2*>(score + 2 * p);
      float wgt = hsel ? __expf(sc.y - m1) * inv1 : __expf(sc.x - m0) * inv0;
      bf16x8 v = *reinterpret_cast<const bf16x8*>(V + (p << 7) + j * 8);
#pragma unroll
      for (int k2 = 0; k2 < 8; ++k2) acc[k2] += wgt * (float)v[k2];
    }
  }
#pragma unroll
  for (int k2 = 0; k2 < 8; ++k2) {
    acc[k2] += __shfl_xor(acc[k2], 16);
    acc[k2] += __shfl_xor(acc[k2], 32);
  }
  if (q == 0) {
    float4 lo = make_float4(acc[0], acc[1], acc[2], acc[3]);
    float4 hi = make_float4(acc[4], acc[5], acc[6], acc[7]);
    float* dst = h + ((size_t)d << 7) + j * 8;
    *reinterpret_cast<float4*>(dst) = lo;
    *reinterpret_cast<float4*>(dst + 4) = hi;
  }
}

extern "C" void kernel_launch(void* const* d_in, const int* in_sizes, int n_in,
                              void* d_out, int out_size, void* d_ws, size_t ws_size,
                              hipStream_t stream) {
  (void)in_sizes; (void)n_in; (void)out_size; (void)ws_size;
  const float* node_h = (const float*)d_in[0];
  const float* edge_f = (const float*)d_in[1];
  const float* dtp    = (const float*)d_in[2];
  const int*   dsti   = (const int*)d_in[3];
  const float* tw     = (const float*)d_in[4];
  const float* tb     = (const float*)d_in[5];
  const float* Wq     = (const float*)d_in[6];
  const float* bq     = (const float*)d_in[7];
  const float* Wk     = (const float*)d_in[8];
  const float* bk     = (const float*)d_in[9];
  const float* Wv     = (const float*)d_in[10];
  const float* bv     = (const float*)d_in[11];
  const float* Wout   = (const float*)d_in[12];
  const float* bout   = (const float*)d_in[13];
  const float* gamma  = (const float*)d_in[14];
  const float* beta   = (const float*)d_in[15];
  float* outp = (float*)d_out;

  size_t off = 0;
  auto take = [&](size_t nbytes) -> void* {
    void* r = (char*)d_ws + off;
    off += (nbytes + 255) & ~(size_t)255;
    return r;
  };
  __bf16* Bq_kv  = (__bf16*)take((size_t)12288 * 16);
  __bf16* Bq_q   = (__bf16*)take((size_t)2048 * 16);
  __bf16* Bq_out = (__bf16*)take((size_t)4096 * 16);
  float*  cq     = (float*)take(128 * 4);
  float*  Qn     = (float*)take((size_t)N_DST * 128 * 4);
  __bf16* Vbuf   = (__bf16*)take((size_t)E_NUM * 128 * 2);
  float*  score  = (float*)take((size_t)E_NUM * 2 * 4);
  int*    counts = (int*)take((size_t)N_DST * 4);
  int*    offs   = (int*)take((size_t)(N_DST + 1) * 4);
  int*    cursor = (int*)take((size_t)N_DST * 4);
  int*    elist  = (int*)take((size_t)E_NUM * 4);
  int*    dsts   = (int*)take((size_t)E_NUM * 4);
  float*  hbuf   = (float*)take((size_t)N_DST * 128 * 4);

  hipMemsetAsync(counts, 0, (size_t)N_DST * 4, stream);

  const int count_blocks = (E_NUM + 255) / 256;
  prep_kernel<<<1 + 48 + 8 + 16 + count_blocks, 256, 0, stream>>>(
      Wq, bq, tb, Wk, Wv, Wout, dsti, cq, Bq_kv, Bq_q, Bq_out, counts);

  gemm_kernel<0><<<(N_DST + 63) / 64, 256, 0, stream>>>(node_h, nullptr, nullptr, nullptr, nullptr,
      Bq_q, cq, nullptr, nullptr, nullptr, nullptr, Qn, nullptr, nullptr);

  scan_kernel<<<1, 1024, 0, stream>>>(counts, offs, cursor);
  fill_kernel<<<count_blocks, 256, 0, stream>>>(dsti, cursor, elist, dsts);

  gemm_kernel<1><<<E_NUM / 64, 256, 0, stream>>>(node_h, edge_f, dtp, tw, tb,
      Bq_kv, bk, bv, elist, dsts, Qn, nullptr, Vbuf, score);

  agg_kernel<<<(N_DST + 3) / 4, 256, 0, stream>>>(offs, score, Vbuf, hbuf);

  gemm_kernel<2><<<(N_DST + 63) / 64, 256, 0, stream>>>(hbuf, node_h, gamma, beta, nullptr,
      Bq_out, bout, nullptr, nullptr, nullptr, nullptr, outp, nullptr, nullptr);
}